// Round 2
// baseline (364.788 us; speedup 1.0000x reference)
//
#include <hip/hip_runtime.h>
#include <hip/hip_bf16.h>

// Problem dims
#define BN 16384
#define FN 256
#define RN 32
#define CN 16
#define H1N 128
#define H2N 32
#define G1N 256
#define G2N 64

typedef __bf16 bf16_t;
typedef __bf16 bf16x8 __attribute__((ext_vector_type(8)));
typedef float f32x4 __attribute__((ext_vector_type(4)));

// ---- workspace byte offsets (all 16B-aligned) ----
#define OFF_DATA   0UL          // data as bf16            [B][F]            8,388,608 B
#define OFF_WF1    8388608UL    // Wf1 packed frags        (H1,F)               65,536
#define OFF_WF2    8454144UL    // Wf2 packed frags        (H2,H1)               8,192
#define OFF_WC1    8462336UL    // Wc1 packed frags        (R,G1,F)          4,194,304
#define OFF_WC2    12656640UL   // Wc2 packed frags        (R,G2,G1)         1,048,576
#define OFF_WC3    13705216UL   // Wc3 packed frags        (R,C,G2)             65,536
#define OFF_FSINI  13770752UL   // fs_ini fp32             [B][R]            2,097,152
#define OFF_C3     15867904UL   // c3 fp32                 [R][B][C]        33,554,432
// total ~49.5 MB

__device__ __forceinline__ f32x4 mfma16(bf16x8 a, bf16x8 b, f32x4 c) {
  return __builtin_amdgcn_mfma_f32_16x16x32_bf16(a, b, c, 0, 0, 0);
}

// A-fragment read from an XOR-swizzled LDS tile (row stride strideB bytes).
// Lane l holds A[m0 + l%16][k0 + 8*(l/16) .. +7]  (guide-verified 16x16x32 layout).
__device__ __forceinline__ bf16x8 afrag(const char* base, int strideB, int m0, int k0, int lane) {
  int row = m0 + (lane & 15);
  int off = (k0 * 2 + ((lane >> 4) << 4)) ^ ((row & 7) << 4);
  return *(const bf16x8*)(base + row * strideB + off);
}

// Pack row-major W[(r,)n,k] fp32 into B-fragment order bf16:
// dst[(((r*KS+ks)*NT+nt)*64+lane)*8 + e] = W[r][nt*16+lane%16][ks*32+(lane/16)*8+e]
__device__ __forceinline__ void pack_frag8(const float* __restrict__ src, bf16_t* __restrict__ dst,
                                           int NT, int KS, int g) {
  int per = NT * KS * 64;
  int r = g / per;
  int local = g - r * per;
  int lane = local & 63;
  int fr = local >> 6;
  int ks = fr / NT;
  int nt = fr - ks * NT;
  int N = NT * 16, K = KS * 32;
  int n = nt * 16 + (lane & 15);
  int k = ks * 32 + ((lane >> 4) << 3);
  const float* s = src + (long)r * N * K + (long)n * K + k;
  float4 a = *(const float4*)s;
  float4 b = *(const float4*)(s + 4);
  bf16x8 o;
  o[0] = (bf16_t)a.x; o[1] = (bf16_t)a.y; o[2] = (bf16_t)a.z; o[3] = (bf16_t)a.w;
  o[4] = (bf16_t)b.x; o[5] = (bf16_t)b.y; o[6] = (bf16_t)b.z; o[7] = (bf16_t)b.w;
  *(bf16x8*)(dst + (long)g * 8) = o;
}

// group counts (each group = 8 elements)
#define G_DATA 524288
#define G_WC1  262144
#define G_WC2  65536
#define G_WF1  4096
#define G_WC3  4096
#define G_WF2  512
#define G_TOTAL (G_DATA + G_WC1 + G_WC2 + G_WF1 + G_WC3 + G_WF2) // 860,672

__global__ __launch_bounds__(256) void k0_pack(
    const float* __restrict__ data, const float* __restrict__ Wf1, const float* __restrict__ Wf2,
    const float* __restrict__ Wc1, const float* __restrict__ Wc2, const float* __restrict__ Wc3,
    char* __restrict__ ws)
{
  int g = blockIdx.x * 256 + threadIdx.x;
  if (g < G_DATA) {
    const float* s = data + (long)g * 8;
    float4 a = *(const float4*)s, b = *(const float4*)(s + 4);
    bf16x8 o;
    o[0] = (bf16_t)a.x; o[1] = (bf16_t)a.y; o[2] = (bf16_t)a.z; o[3] = (bf16_t)a.w;
    o[4] = (bf16_t)b.x; o[5] = (bf16_t)b.y; o[6] = (bf16_t)b.z; o[7] = (bf16_t)b.w;
    *(bf16x8*)((bf16_t*)(ws + OFF_DATA) + (long)g * 8) = o;
    return;
  }
  g -= G_DATA;
  if (g < G_WC1) { pack_frag8(Wc1, (bf16_t*)(ws + OFF_WC1), 16, 8, g); return; }
  g -= G_WC1;
  if (g < G_WC2) { pack_frag8(Wc2, (bf16_t*)(ws + OFF_WC2), 4, 8, g); return; }
  g -= G_WC2;
  if (g < G_WF1) { pack_frag8(Wf1, (bf16_t*)(ws + OFF_WF1), 8, 8, g); return; }
  g -= G_WF1;
  if (g < G_WC3) { pack_frag8(Wc3, (bf16_t*)(ws + OFF_WC3), 1, 2, g); return; }
  g -= G_WC3;
  if (g < G_WF2) { pack_frag8(Wf2, (bf16_t*)(ws + OFF_WF2), 2, 4, g); return; }
}

// K1: per (rule, 128-row tile): membership (fp32 exp -> bf16 LDS) -> h1 -> h2 -> fs_ini
__global__ __launch_bounds__(512) void k1_fs(
    const float* __restrict__ data, const float* __restrict__ proto, const float* __restrict__ var,
    const float* __restrict__ bf1g, const float* __restrict__ bf2g,
    const float* __restrict__ Wf3g, const float* __restrict__ bf3g,
    const bf16_t* __restrict__ Wf1p, const bf16_t* __restrict__ Wf2p,
    float* __restrict__ fsini)
{
  __shared__ float proto_s[FN];
  __shared__ float ivar_s[FN];
  __shared__ char mem_lds[128 * 512];   // bf16 [128][256], XOR-swizzled
  __shared__ char h1_lds[128 * 256];    // bf16 [128][128], XOR-swizzled
  __shared__ float h2_lds[128][H2N + 4];

  const int r   = blockIdx.x >> 7;
  const int b0  = (blockIdx.x & 127) << 7;
  const int tid = threadIdx.x;
  const int lane = tid & 63;
  const int w   = tid >> 6;

  if (tid < FN) {
    proto_s[tid] = proto[r * FN + tid];
    float v = var[r * FN + tid];
    v = fminf(fmaxf(v, 1e-4f), 0.1f);
    ivar_s[tid] = 1.4426950408889634f * 0.5f / (v * v);  // log2(e)/(2 v^2)
  }
  __syncthreads();

  { // membership: mem = exp2(-(x-p)^2 * ivar)
    const int row = tid >> 2;
    const int f0  = (tid & 3) << 6;
    const float* dp = data + (long)(b0 + row) * FN + f0;
    char* mrow = mem_lds + row * 512;
    const int sw = (row & 7) << 4;
    #pragma unroll
    for (int i = 0; i < 8; ++i) {
      const int f = f0 + i * 8;
      float4 x0 = *(const float4*)(dp + i * 8);
      float4 x1 = *(const float4*)(dp + i * 8 + 4);
      bf16x8 m; float d;
      d = x0.x - proto_s[f + 0]; m[0] = (bf16_t)exp2f(-d * d * ivar_s[f + 0]);
      d = x0.y - proto_s[f + 1]; m[1] = (bf16_t)exp2f(-d * d * ivar_s[f + 1]);
      d = x0.z - proto_s[f + 2]; m[2] = (bf16_t)exp2f(-d * d * ivar_s[f + 2]);
      d = x0.w - proto_s[f + 3]; m[3] = (bf16_t)exp2f(-d * d * ivar_s[f + 3]);
      d = x1.x - proto_s[f + 4]; m[4] = (bf16_t)exp2f(-d * d * ivar_s[f + 4]);
      d = x1.y - proto_s[f + 5]; m[5] = (bf16_t)exp2f(-d * d * ivar_s[f + 5]);
      d = x1.z - proto_s[f + 6]; m[6] = (bf16_t)exp2f(-d * d * ivar_s[f + 6]);
      d = x1.w - proto_s[f + 7]; m[7] = (bf16_t)exp2f(-d * d * ivar_s[f + 7]);
      *(bf16x8*)(mrow + ((f * 2) ^ sw)) = m;
    }
  }
  __syncthreads();

  // GEMM1: h1[128][128] = mem @ Wf1^T ; 8 waves = 2M x 4N (wave: 64 rows x 32 cols)
  const int wm = w >> 2;  // 0..1
  const int wn = w & 3;   // 0..3
  f32x4 acc[4][2] = {};
  #pragma unroll
  for (int ks = 0; ks < 8; ++ks) {
    bf16x8 a[4], bb[2];
    #pragma unroll
    for (int j = 0; j < 2; ++j)
      bb[j] = *(const bf16x8*)(Wf1p + ((ks * 8 + wn * 2 + j) * 64 + lane) * 8);
    #pragma unroll
    for (int i = 0; i < 4; ++i)
      a[i] = afrag(mem_lds, 512, wm * 64 + i * 16, ks * 32, lane);
    #pragma unroll
    for (int i = 0; i < 4; ++i)
      #pragma unroll
      for (int j = 0; j < 2; ++j)
        acc[i][j] = mfma16(a[i], bb[j], acc[i][j]);
  }
  #pragma unroll
  for (int j = 0; j < 2; ++j) {  // h1 epilogue: relu(acc+bias) -> bf16 LDS
    const int col = wn * 32 + j * 16 + (lane & 15);
    const float bias = bf1g[col];
    #pragma unroll
    for (int i = 0; i < 4; ++i)
      #pragma unroll
      for (int q = 0; q < 4; ++q) {
        int row = wm * 64 + i * 16 + ((lane >> 4) << 2) + q;
        float v = fmaxf(acc[i][j][q] + bias, 0.f);
        *(bf16_t*)(h1_lds + row * 256 + ((col * 2) ^ ((row & 7) << 4))) = (bf16_t)v;
      }
  }
  __syncthreads();

  // GEMM2: h2[128][32] = h1 @ Wf2^T ; 8 waves = 4M x 2N
  const int wm2 = w >> 1;  // 0..3
  const int wn2 = w & 1;   // 0..1
  f32x4 acc2[2] = {};
  #pragma unroll
  for (int ks = 0; ks < 4; ++ks) {
    bf16x8 bb = *(const bf16x8*)(Wf2p + ((ks * 2 + wn2) * 64 + lane) * 8);
    #pragma unroll
    for (int i = 0; i < 2; ++i) {
      bf16x8 a = afrag(h1_lds, 256, wm2 * 32 + i * 16, ks * 32, lane);
      acc2[i] = mfma16(a, bb, acc2[i]);
    }
  }
  {
    const int col = wn2 * 16 + (lane & 15);
    const float bias = bf2g[col];
    #pragma unroll
    for (int i = 0; i < 2; ++i)
      #pragma unroll
      for (int q = 0; q < 4; ++q) {
        int row = wm2 * 32 + i * 16 + ((lane >> 4) << 2) + q;
        h2_lds[row][col] = fmaxf(acc2[i][q] + bias, 0.f);
      }
  }
  __syncthreads();

  if (tid < 128) { // fs = relu(h2 . Wf3 + bf3)
    float s = bf3g[0];
    #pragma unroll
    for (int p = 0; p < H2N; ++p) s += h2_lds[tid][p] * Wf3g[p];
    fsini[(long)(b0 + tid) * RN + r] = fmaxf(s, 0.f);
  }
}

__global__ __launch_bounds__(256) void k2_softmax(const float* __restrict__ fsini,
                                                  float* __restrict__ fire)
{
  int b = blockIdx.x * 256 + threadIdx.x;
  float v[RN];
  const float4* p = (const float4*)(fsini + (long)b * RN);
  #pragma unroll
  for (int i = 0; i < RN / 4; ++i) {
    float4 t = p[i];
    v[4 * i] = t.x; v[4 * i + 1] = t.y; v[4 * i + 2] = t.z; v[4 * i + 3] = t.w;
  }
  float m = v[0];
  #pragma unroll
  for (int i = 1; i < RN; ++i) m = fmaxf(m, v[i]);
  float s = 0.f;
  #pragma unroll
  for (int i = 0; i < RN; ++i) { v[i] = expf(v[i] - m); s += v[i]; }
  float inv = 1.f / s;
  float4* o = (float4*)(fire + (long)b * RN);
  #pragma unroll
  for (int i = 0; i < RN / 4; ++i) {
    float4 t; t.x = v[4 * i] * inv; t.y = v[4 * i + 1] * inv;
    t.z = v[4 * i + 2] * inv; t.w = v[4 * i + 3] * inv;
    o[i] = t;
  }
}

// K3: per (rule, 128-row tile): c1=elu(data@Wc1^T) -> c2=elu(c1@Wc2^T) -> c3=relu(c2@Wc3^T)
__global__ __launch_bounds__(512, 4) void k3_cons(
    const bf16_t* __restrict__ datab,
    const bf16_t* __restrict__ Wc1p, const bf16_t* __restrict__ Wc2p, const bf16_t* __restrict__ Wc3p,
    const float* __restrict__ bc1, const float* __restrict__ bc2, const float* __restrict__ bc3,
    float* __restrict__ c3buf)
{
  __shared__ char a_lds[128 * 512];   // bf16 [128][256] swizzled: data, then reused for c1
  __shared__ char c2_lds[128 * 128];  // bf16 [128][64] swizzled

  const int r   = blockIdx.x >> 7;
  const int b0  = (blockIdx.x & 127) << 7;
  const int tid = threadIdx.x;
  const int lane = tid & 63;
  const int w   = tid >> 6;

  { // stage data tile
    const int row = tid >> 2;
    const int e0  = (tid & 3) << 6;
    const bf16_t* sp = datab + (long)(b0 + row) * FN + e0;
    char* drow = a_lds + row * 512;
    const int sw = (row & 7) << 4;
    #pragma unroll
    for (int i = 0; i < 8; ++i) {
      bf16x8 v = *(const bf16x8*)(sp + i * 8);
      *(bf16x8*)(drow + (((e0 + i * 8) * 2) ^ sw)) = v;
    }
  }
  __syncthreads();

  const int wm = w >> 2;  // 0..1
  const int wn = w & 3;   // 0..3

  // GEMM1: c1[128][256] = data @ Wc1[r]^T ; 2M x 4N (wave: 64 rows x 64 cols)
  const bf16_t* W1 = Wc1p + (long)r * G1N * FN;
  f32x4 acc[4][4] = {};
  #pragma unroll
  for (int ks = 0; ks < 8; ++ks) {
    bf16x8 a[4], bb[4];
    #pragma unroll
    for (int j = 0; j < 4; ++j)
      bb[j] = *(const bf16x8*)(W1 + ((ks * 16 + wn * 4 + j) * 64 + lane) * 8);
    #pragma unroll
    for (int i = 0; i < 4; ++i)
      a[i] = afrag(a_lds, 512, wm * 64 + i * 16, ks * 32, lane);
    #pragma unroll
    for (int i = 0; i < 4; ++i)
      #pragma unroll
      for (int j = 0; j < 4; ++j)
        acc[i][j] = mfma16(a[i], bb[j], acc[i][j]);
  }
  __syncthreads();  // everyone done reading the data tile

  #pragma unroll
  for (int j = 0; j < 4; ++j) {  // c1 epilogue: elu -> bf16, overwrite a_lds
    const int col = wn * 64 + j * 16 + (lane & 15);
    const float bias = bc1[r * G1N + col];
    #pragma unroll
    for (int i = 0; i < 4; ++i)
      #pragma unroll
      for (int q = 0; q < 4; ++q) {
        int row = wm * 64 + i * 16 + ((lane >> 4) << 2) + q;
        float v = acc[i][j][q] + bias;
        v = (v > 0.f) ? v : expm1f(v);
        *(bf16_t*)(a_lds + row * 512 + ((col * 2) ^ ((row & 7) << 4))) = (bf16_t)v;
      }
  }
  __syncthreads();

  // GEMM2: c2[128][64] = c1 @ Wc2[r]^T ; 2M x 4N (wave: 64 rows x 16 cols)
  const bf16_t* W2 = Wc2p + (long)r * G2N * G1N;
  f32x4 acc2[4] = {};
  #pragma unroll
  for (int ks = 0; ks < 8; ++ks) {
    bf16x8 bb = *(const bf16x8*)(W2 + ((ks * 4 + wn) * 64 + lane) * 8);
    #pragma unroll
    for (int i = 0; i < 4; ++i) {
      bf16x8 a = afrag(a_lds, 512, wm * 64 + i * 16, ks * 32, lane);
      acc2[i] = mfma16(a, bb, acc2[i]);
    }
  }
  {
    const int col = wn * 16 + (lane & 15);
    const float bias = bc2[r * G2N + col];
    #pragma unroll
    for (int i = 0; i < 4; ++i)
      #pragma unroll
      for (int q = 0; q < 4; ++q) {
        int row = wm * 64 + i * 16 + ((lane >> 4) << 2) + q;
        float v = acc2[i][q] + bias;
        v = (v > 0.f) ? v : expm1f(v);
        *(bf16_t*)(c2_lds + row * 128 + ((col * 2) ^ ((row & 7) << 4))) = (bf16_t)v;
      }
  }
  __syncthreads();

  // GEMM3: c3[128][16] = c2 @ Wc3[r]^T ; wave w owns rows w*16..+16
  const bf16_t* W3 = Wc3p + (long)r * CN * G2N;
  f32x4 acc3 = {};
  #pragma unroll
  for (int ks = 0; ks < 2; ++ks) {
    bf16x8 a = afrag(c2_lds, 128, w * 16, ks * 32, lane);
    bf16x8 bb = *(const bf16x8*)(W3 + ((long)ks * 64 + lane) * 8);
    acc3 = mfma16(a, bb, acc3);
  }
  {
    const int col = lane & 15;
    const float bias = bc3[r * CN + col];
    float* op = c3buf + ((long)r * BN + b0) * CN;
    #pragma unroll
    for (int q = 0; q < 4; ++q) {
      int row = w * 16 + ((lane >> 4) << 2) + q;
      op[(long)row * CN + col] = fmaxf(acc3[q] + bias, 0.f);
    }
  }
}

__global__ __launch_bounds__(256) void k4_out(const float* __restrict__ c3buf,
                                              const float* __restrict__ fire,
                                              float* __restrict__ out)
{
  int t = blockIdx.x * 256 + threadIdx.x;  // over B*C
  int b = t >> 4, c = t & 15;
  const float* fp = fire + (long)b * RN;
  float s = 0.f;
  #pragma unroll
  for (int rr = 0; rr < RN; ++rr)
    s += fp[rr] * c3buf[((long)rr * BN + b) * CN + c];
  out[t] = s;
}

extern "C" void kernel_launch(void* const* d_in, const int* in_sizes, int n_in,
                              void* d_out, int out_size, void* d_ws, size_t ws_size,
                              hipStream_t stream) {
  const float* data = (const float*)d_in[0];
  const float* proto = (const float*)d_in[1];
  const float* var  = (const float*)d_in[2];
  const float* Wf1  = (const float*)d_in[3];
  const float* bf1  = (const float*)d_in[4];
  const float* Wf2  = (const float*)d_in[5];
  const float* bf2  = (const float*)d_in[6];
  const float* Wf3  = (const float*)d_in[7];
  const float* bf3  = (const float*)d_in[8];
  const float* Wc1  = (const float*)d_in[9];
  const float* bc1  = (const float*)d_in[10];
  const float* Wc2  = (const float*)d_in[11];
  const float* bc2  = (const float*)d_in[12];
  const float* Wc3  = (const float*)d_in[13];
  const float* bc3  = (const float*)d_in[14];

  char* ws = (char*)d_ws;
  bf16_t* datab = (bf16_t*)(ws + OFF_DATA);
  bf16_t* Wf1p  = (bf16_t*)(ws + OFF_WF1);
  bf16_t* Wf2p  = (bf16_t*)(ws + OFF_WF2);
  bf16_t* Wc1p  = (bf16_t*)(ws + OFF_WC1);
  bf16_t* Wc2p  = (bf16_t*)(ws + OFF_WC2);
  bf16_t* Wc3p  = (bf16_t*)(ws + OFF_WC3);
  float*  fsini = (float*)(ws + OFF_FSINI);
  float*  c3buf = (float*)(ws + OFF_C3);

  float* out  = (float*)d_out;               // [B][C]
  float* fire = out + (long)BN * CN;         // [B][R]

  k0_pack<<<G_TOTAL / 256, 256, 0, stream>>>(data, Wf1, Wf2, Wc1, Wc2, Wc3, ws);
  k1_fs<<<RN * (BN / 128), 512, 0, stream>>>(data, proto, var, bf1, bf2, Wf3, bf3,
                                             Wf1p, Wf2p, fsini);
  k2_softmax<<<BN / 256, 256, 0, stream>>>(fsini, fire);
  k3_cons<<<RN * (BN / 128), 512, 0, stream>>>(datab, Wc1p, Wc2p, Wc3p, bc1, bc2, bc3, c3buf);
  k4_out<<<(BN * CN) / 256, 256, 0, stream>>>(c3buf, fire, out);
}

// Round 3
// 264.879 us; speedup vs baseline: 1.3772x; 1.3772x over previous
//
#include <hip/hip_runtime.h>
#include <hip/hip_bf16.h>

// Problem dims
#define BN 16384
#define FN 256
#define RN 32
#define CN 16
#define H1N 128
#define H2N 32
#define G1N 256
#define G2N 64

typedef __bf16 bf16_t;
typedef __bf16 bf16x8 __attribute__((ext_vector_type(8)));
typedef __bf16 bf16x4 __attribute__((ext_vector_type(4)));
typedef float f32x4 __attribute__((ext_vector_type(4)));

// ---- workspace byte offsets (all 16B-aligned) ----
#define OFF_DATA   0UL          // data as bf16            [B][F]            8,388,608 B
#define OFF_WF1    8388608UL    // Wf1 packed frags        (H1,F)               65,536
#define OFF_WF2    8454144UL    // Wf2 packed frags        (H2,H1)               8,192
#define OFF_WC1    8462336UL    // Wc1 packed frags        (R,G1,F)          4,194,304
#define OFF_WC2    12656640UL   // Wc2 packed frags        (R,G2,G1)         1,048,576
#define OFF_WC3    13705216UL   // Wc3 packed frags        (R,C,G2)             65,536
#define OFF_FSINI  13770752UL   // fs_ini fp32             [B][R]            2,097,152
#define OFF_C3     15867904UL   // c3 fp32                 [R][B][C]        33,554,432

__device__ __forceinline__ f32x4 mfma16(bf16x8 a, bf16x8 b, f32x4 c) {
  return __builtin_amdgcn_mfma_f32_16x16x32_bf16(a, b, c, 0, 0, 0);
}

// Fast ELU: exp2(v*log2e)-1 (1 TRANS + mul + add + select) instead of expm1f libcall.
__device__ __forceinline__ float elu_f(float v) {
  float e = __builtin_amdgcn_exp2f(v * 1.44269504f) - 1.0f;
  return v > 0.f ? v : e;
}

// B-fragment read from an XOR-swizzled LDS tile [row][k] (row stride strideB bytes).
// Lane l gets element (row = n0 + l%16, k = k0 + 8*(l/16) + e) — identical lane map to A-frag.
__device__ __forceinline__ bf16x8 lfrag(const char* base, int strideB, int n0, int k0, int lane) {
  int row = n0 + (lane & 15);
  int off = (k0 * 2 + ((lane >> 4) << 4)) ^ ((row & 7) << 4);
  return *(const bf16x8*)(base + row * strideB + off);
}

// Pack row-major W[(r,)n,k] fp32 into fragment order bf16 (serves as A- or B-frag):
// dst[(((r*KS+ks)*NT+nt)*64+lane)*8 + e] = W[r][nt*16+lane%16][ks*32+(lane/16)*8+e]
__device__ __forceinline__ void pack_frag8(const float* __restrict__ src, bf16_t* __restrict__ dst,
                                           int NT, int KS, int g) {
  int per = NT * KS * 64;
  int r = g / per;
  int local = g - r * per;
  int lane = local & 63;
  int fr = local >> 6;
  int ks = fr / NT;
  int nt = fr - ks * NT;
  int N = NT * 16, K = KS * 32;
  int n = nt * 16 + (lane & 15);
  int k = ks * 32 + ((lane >> 4) << 3);
  const float* s = src + (long)r * N * K + (long)n * K + k;
  float4 a = *(const float4*)s;
  float4 b = *(const float4*)(s + 4);
  bf16x8 o;
  o[0] = (bf16_t)a.x; o[1] = (bf16_t)a.y; o[2] = (bf16_t)a.z; o[3] = (bf16_t)a.w;
  o[4] = (bf16_t)b.x; o[5] = (bf16_t)b.y; o[6] = (bf16_t)b.z; o[7] = (bf16_t)b.w;
  *(bf16x8*)(dst + (long)g * 8) = o;
}

// group counts (each group = 8 elements)
#define G_DATA 524288
#define G_WC1  262144
#define G_WC2  65536
#define G_WF1  4096
#define G_WC3  4096
#define G_WF2  512
#define G_TOTAL (G_DATA + G_WC1 + G_WC2 + G_WF1 + G_WC3 + G_WF2) // 860,672

__global__ __launch_bounds__(256) void k0_pack(
    const float* __restrict__ data, const float* __restrict__ Wf1, const float* __restrict__ Wf2,
    const float* __restrict__ Wc1, const float* __restrict__ Wc2, const float* __restrict__ Wc3,
    char* __restrict__ ws)
{
  int g = blockIdx.x * 256 + threadIdx.x;
  if (g < G_DATA) {
    const float* s = data + (long)g * 8;
    float4 a = *(const float4*)s, b = *(const float4*)(s + 4);
    bf16x8 o;
    o[0] = (bf16_t)a.x; o[1] = (bf16_t)a.y; o[2] = (bf16_t)a.z; o[3] = (bf16_t)a.w;
    o[4] = (bf16_t)b.x; o[5] = (bf16_t)b.y; o[6] = (bf16_t)b.z; o[7] = (bf16_t)b.w;
    *(bf16x8*)((bf16_t*)(ws + OFF_DATA) + (long)g * 8) = o;
    return;
  }
  g -= G_DATA;
  if (g < G_WC1) { pack_frag8(Wc1, (bf16_t*)(ws + OFF_WC1), 16, 8, g); return; }
  g -= G_WC1;
  if (g < G_WC2) { pack_frag8(Wc2, (bf16_t*)(ws + OFF_WC2), 4, 8, g); return; }
  g -= G_WC2;
  if (g < G_WF1) { pack_frag8(Wf1, (bf16_t*)(ws + OFF_WF1), 8, 8, g); return; }
  g -= G_WF1;
  if (g < G_WC3) { pack_frag8(Wc3, (bf16_t*)(ws + OFF_WC3), 1, 2, g); return; }
  g -= G_WF2 + G_WC3 - G_WC3; // fallthrough arithmetic kept explicit below
  if (g < G_WC3) { } // unreachable
  g -= 0;
  { // remaining: Wf2
    // g currently = original - G_DATA - G_WC1 - G_WC2 - G_WF1 - G_WC3
    if (g >= G_WC3) { g -= G_WC3; }
    if (g < G_WF2) { pack_frag8(Wf2, (bf16_t*)(ws + OFF_WF2), 2, 4, g); return; }
  }
}

// K1: per (rule, 128-row tile): membership -> h1T -> h2T -> fs_ini
// Transposed GEMMs: A = packed weights (M=feature), B = activations (N=batch).
// LDS overlay: h1T/h2 reuse the membership tile after it is dead (saves 50 KiB -> 2 blocks/CU).
__global__ __launch_bounds__(512, 4) void k1_fs(
    const float* __restrict__ data, const float* __restrict__ proto, const float* __restrict__ var,
    const float* __restrict__ bf1g, const float* __restrict__ bf2g,
    const float* __restrict__ Wf3g, const float* __restrict__ bf3g,
    const bf16_t* __restrict__ Wf1p, const bf16_t* __restrict__ Wf2p,
    float* __restrict__ fsini)
{
  __shared__ float proto_s[FN];
  __shared__ float ivar_s[FN];
  __shared__ __attribute__((aligned(16))) char mem_lds[128 * 512]; // mem [b][f]; later h1T [b][h] (32KB) + h2 (20KB)

  const int r   = blockIdx.x >> 7;
  const int b0  = (blockIdx.x & 127) << 7;
  const int tid = threadIdx.x;
  const int lane = tid & 63;
  const int w   = tid >> 6;

  if (tid < FN) {
    proto_s[tid] = proto[r * FN + tid];
    float v = var[r * FN + tid];
    v = fminf(fmaxf(v, 1e-4f), 0.1f);
    ivar_s[tid] = 1.4426950408889634f * 0.5f / (v * v);  // log2(e)/(2 v^2)
  }
  __syncthreads();

  { // membership: mem[b][f] = exp2(-(x-p)^2 * ivar), bf16, XOR-swizzled
    const int row = tid >> 2;
    const int f0  = (tid & 3) << 6;
    const float* dp = data + (long)(b0 + row) * FN + f0;
    char* mrow = mem_lds + row * 512;
    const int sw = (row & 7) << 4;
    #pragma unroll
    for (int i = 0; i < 8; ++i) {
      const int f = f0 + i * 8;
      float4 x0 = *(const float4*)(dp + i * 8);
      float4 x1 = *(const float4*)(dp + i * 8 + 4);
      bf16x8 m; float d;
      d = x0.x - proto_s[f + 0]; m[0] = (bf16_t)__builtin_amdgcn_exp2f(-d * d * ivar_s[f + 0]);
      d = x0.y - proto_s[f + 1]; m[1] = (bf16_t)__builtin_amdgcn_exp2f(-d * d * ivar_s[f + 1]);
      d = x0.z - proto_s[f + 2]; m[2] = (bf16_t)__builtin_amdgcn_exp2f(-d * d * ivar_s[f + 2]);
      d = x0.w - proto_s[f + 3]; m[3] = (bf16_t)__builtin_amdgcn_exp2f(-d * d * ivar_s[f + 3]);
      d = x1.x - proto_s[f + 4]; m[4] = (bf16_t)__builtin_amdgcn_exp2f(-d * d * ivar_s[f + 4]);
      d = x1.y - proto_s[f + 5]; m[5] = (bf16_t)__builtin_amdgcn_exp2f(-d * d * ivar_s[f + 5]);
      d = x1.z - proto_s[f + 6]; m[6] = (bf16_t)__builtin_amdgcn_exp2f(-d * d * ivar_s[f + 6]);
      d = x1.w - proto_s[f + 7]; m[7] = (bf16_t)__builtin_amdgcn_exp2f(-d * d * ivar_s[f + 7]);
      *(bf16x8*)(mrow + ((f * 2) ^ sw)) = m;
    }
  }
  __syncthreads();

  // GEMM1: h1T[h=128][b=128] = Wf1 @ memT. A=Wf1p (8 m-tiles), B=mem (8 n-tiles).
  // wave: wm = w>>2 (m0 = wm*64, 4 m-tiles), wn = w&3 (n0 = wn*32, 2 n-tiles)
  const int wm = w >> 2;
  const int wn = w & 3;
  f32x4 acc[4][2] = {};
  #pragma unroll
  for (int ks = 0; ks < 8; ++ks) {
    bf16x8 a[4], bb[2];
    #pragma unroll
    for (int i = 0; i < 4; ++i)
      a[i] = *(const bf16x8*)(Wf1p + (((ks * 8 + wm * 4 + i) * 64 + lane)) * 8);
    #pragma unroll
    for (int j = 0; j < 2; ++j)
      bb[j] = lfrag(mem_lds, 512, wn * 32 + j * 16, ks * 32, lane);
    #pragma unroll
    for (int i = 0; i < 4; ++i)
      #pragma unroll
      for (int j = 0; j < 2; ++j)
        acc[i][j] = mfma16(a[i], bb[j], acc[i][j]);
  }
  __syncthreads();   // membership tile now dead — safe to overwrite with h1T

  // h1T epilogue: relu(acc+bias) -> bf16 [b][h] (row stride 256B), one b64 per lane per tile
  #pragma unroll
  for (int i = 0; i < 4; ++i) {
    const int hb = wm * 64 + i * 16 + ((lane >> 4) << 2);  // 4 consecutive h rows
    f32x4 bias = *(const f32x4*)(bf1g + hb);
    #pragma unroll
    for (int j = 0; j < 2; ++j) {
      const int b = wn * 32 + j * 16 + (lane & 15);
      bf16x4 o;
      #pragma unroll
      for (int q = 0; q < 4; ++q)
        o[q] = (bf16_t)fmaxf(acc[i][j][q] + bias[q], 0.f);
      *(bf16x4*)(mem_lds + b * 256 + ((hb * 2) ^ ((b & 7) << 4))) = o;
    }
  }
  __syncthreads();

  // GEMM2: h2T[p=32][b=128] = Wf2 @ h1T. 16 tiles: wave: mt = w>>2 (0..1), n-tiles (w&3)*2+{0,1}
  float* h2s = (float*)(mem_lds + 32768);  // [128][40] fp32
  const int mt = w >> 2;
  f32x4 acc2[2] = {};
  #pragma unroll
  for (int ks = 0; ks < 4; ++ks) {
    bf16x8 a = *(const bf16x8*)(Wf2p + (((ks * 2 + mt) * 64 + lane)) * 8);
    #pragma unroll
    for (int j = 0; j < 2; ++j) {
      bf16x8 bb = lfrag(mem_lds, 256, (w & 3) * 32 + j * 16, ks * 32, lane);
      acc2[j] = mfma16(a, bb, acc2[j]);
    }
  }
  {
    const int p0 = mt * 16 + ((lane >> 4) << 2);
    f32x4 bias = *(const f32x4*)(bf2g + p0);
    #pragma unroll
    for (int j = 0; j < 2; ++j) {
      const int b = (w & 3) * 32 + j * 16 + (lane & 15);
      f32x4 o;
      #pragma unroll
      for (int q = 0; q < 4; ++q) o[q] = fmaxf(acc2[j][q] + bias[q], 0.f);
      *(f32x4*)(h2s + b * 40 + p0) = o;
    }
  }
  __syncthreads();

  if (tid < 128) { // fs = relu(h2 . Wf3 + bf3)
    float s = bf3g[0];
    const float* hrow = h2s + tid * 40;
    #pragma unroll
    for (int p = 0; p < H2N; ++p) s += hrow[p] * Wf3g[p];
    fsini[(long)(b0 + tid) * RN + r] = fmaxf(s, 0.f);
  }
}

__global__ __launch_bounds__(256) void k2_softmax(const float* __restrict__ fsini,
                                                  float* __restrict__ fire)
{
  int b = blockIdx.x * 256 + threadIdx.x;
  float v[RN];
  const float4* p = (const float4*)(fsini + (long)b * RN);
  #pragma unroll
  for (int i = 0; i < RN / 4; ++i) {
    float4 t = p[i];
    v[4 * i] = t.x; v[4 * i + 1] = t.y; v[4 * i + 2] = t.z; v[4 * i + 3] = t.w;
  }
  float m = v[0];
  #pragma unroll
  for (int i = 1; i < RN; ++i) m = fmaxf(m, v[i]);
  float s = 0.f;
  #pragma unroll
  for (int i = 0; i < RN; ++i) { v[i] = expf(v[i] - m); s += v[i]; }
  float inv = 1.f / s;
  float4* o = (float4*)(fire + (long)b * RN);
  #pragma unroll
  for (int i = 0; i < RN / 4; ++i) {
    float4 t; t.x = v[4 * i] * inv; t.y = v[4 * i + 1] * inv;
    t.z = v[4 * i + 2] * inv; t.w = v[4 * i + 3] * inv;
    o[i] = t;
  }
}

// K3: transposed chain: c1T = Wc1@dataT -> c2T = Wc2@c1T -> c3T = Wc3@c2T.
// Epilogues write b64 (4 consecutive feature values per lane); final store is float4.
__global__ __launch_bounds__(512, 4) void k3_cons(
    const bf16_t* __restrict__ datab,
    const bf16_t* __restrict__ Wc1p, const bf16_t* __restrict__ Wc2p, const bf16_t* __restrict__ Wc3p,
    const float* __restrict__ bc1, const float* __restrict__ bc2, const float* __restrict__ bc3,
    float* __restrict__ c3buf)
{
  __shared__ __attribute__((aligned(16))) char a_lds[128 * 512];   // data [b][f] then c1T [b][g1]
  __shared__ __attribute__((aligned(16))) char c2_lds[128 * 128];  // c2T [b][g2] bf16

  const int r   = blockIdx.x >> 7;
  const int b0  = (blockIdx.x & 127) << 7;
  const int tid = threadIdx.x;
  const int lane = tid & 63;
  const int w   = tid >> 6;

  { // stage data tile [b][f] swizzled
    const int row = tid >> 2;
    const int e0  = (tid & 3) << 6;
    const bf16_t* sp = datab + (long)(b0 + row) * FN + e0;
    char* drow = a_lds + row * 512;
    const int sw = (row & 7) << 4;
    #pragma unroll
    for (int i = 0; i < 8; ++i) {
      bf16x8 v = *(const bf16x8*)(sp + i * 8);
      *(bf16x8*)(drow + (((e0 + i * 8) * 2) ^ sw)) = v;
    }
  }
  __syncthreads();

  // GEMM1: c1T[g1=256][b=128]. A=Wc1p (16 m-tiles), B=data (8 n-tiles).
  // wave: wm = w>>1 (m0 = wm*64, 4 m-tiles), wn = w&1 (n0 = wn*64, 4 n-tiles)
  const int wm = w >> 1;
  const int wn = w & 1;
  const bf16_t* W1 = Wc1p + (long)r * G1N * FN;
  f32x4 acc[4][4] = {};
  #pragma unroll
  for (int ks = 0; ks < 8; ++ks) {
    bf16x8 a[4], bb[4];
    #pragma unroll
    for (int i = 0; i < 4; ++i)
      a[i] = *(const bf16x8*)(W1 + (((ks * 16 + wm * 4 + i) * 64 + lane)) * 8);
    #pragma unroll
    for (int j = 0; j < 4; ++j)
      bb[j] = lfrag(a_lds, 512, wn * 64 + j * 16, ks * 32, lane);
    #pragma unroll
    for (int i = 0; i < 4; ++i)
      #pragma unroll
      for (int j = 0; j < 4; ++j)
        acc[i][j] = mfma16(a[i], bb[j], acc[i][j]);
  }
  __syncthreads();  // data tile dead

  // c1T epilogue: elu(acc+bias) -> bf16 [b][g1], one b64 per lane per tile
  #pragma unroll
  for (int i = 0; i < 4; ++i) {
    const int g1b = wm * 64 + i * 16 + ((lane >> 4) << 2);
    f32x4 bias = *(const f32x4*)(bc1 + r * G1N + g1b);
    #pragma unroll
    for (int j = 0; j < 4; ++j) {
      const int b = wn * 64 + j * 16 + (lane & 15);
      bf16x4 o;
      #pragma unroll
      for (int q = 0; q < 4; ++q)
        o[q] = (bf16_t)elu_f(acc[i][j][q] + bias[q]);
      *(bf16x4*)(a_lds + b * 512 + ((g1b * 2) ^ ((b & 7) << 4))) = o;
    }
  }
  __syncthreads();

  // GEMM2: c2T[g2=64][b=128]. A=Wc2p (4 m-tiles), B=c1T (8 n-tiles). 32 tiles / 8 waves.
  // wave: wm2 = w>>2 (2 m-tiles), wn2 = w&3 (2 n-tiles)
  const int wm2 = w >> 2;
  const int wn2 = w & 3;
  const bf16_t* W2 = Wc2p + (long)r * G2N * G1N;
  f32x4 acc2[2][2] = {};
  #pragma unroll
  for (int ks = 0; ks < 8; ++ks) {
    bf16x8 a[2], bb[2];
    #pragma unroll
    for (int i = 0; i < 2; ++i)
      a[i] = *(const bf16x8*)(W2 + (((ks * 4 + wm2 * 2 + i) * 64 + lane)) * 8);
    #pragma unroll
    for (int j = 0; j < 2; ++j)
      bb[j] = lfrag(a_lds, 512, wn2 * 32 + j * 16, ks * 32, lane);
    #pragma unroll
    for (int i = 0; i < 2; ++i)
      #pragma unroll
      for (int j = 0; j < 2; ++j)
        acc2[i][j] = mfma16(a[i], bb[j], acc2[i][j]);
  }
  #pragma unroll
  for (int i = 0; i < 2; ++i) {
    const int g2b = wm2 * 32 + i * 16 + ((lane >> 4) << 2);
    f32x4 bias = *(const f32x4*)(bc2 + r * G2N + g2b);
    #pragma unroll
    for (int j = 0; j < 2; ++j) {
      const int b = wn2 * 32 + j * 16 + (lane & 15);
      bf16x4 o;
      #pragma unroll
      for (int q = 0; q < 4; ++q)
        o[q] = (bf16_t)elu_f(acc2[i][j][q] + bias[q]);
      *(bf16x4*)(c2_lds + b * 128 + ((g2b * 2) ^ ((b & 7) << 4))) = o;
    }
  }
  __syncthreads();

  // GEMM3: c3T[c=16][b=128]. A=Wc3p (1 m-tile), B=c2T (wave w -> n0 = w*16). K=64.
  const bf16_t* W3 = Wc3p + (long)r * CN * G2N;
  f32x4 acc3 = {};
  #pragma unroll
  for (int ks = 0; ks < 2; ++ks) {
    bf16x8 a = *(const bf16x8*)(W3 + (((long)ks * 64 + lane)) * 8);
    bf16x8 bb = lfrag(c2_lds, 128, w * 16, ks * 32, lane);
    acc3 = mfma16(a, bb, acc3);
  }
  { // relu + bias, float4 store: lane holds c = c0..c0+3 at batch row b
    const int c0 = ((lane >> 4) << 2);
    const int b  = w * 16 + (lane & 15);
    f32x4 bias = *(const f32x4*)(bc3 + r * CN + c0);
    f32x4 o;
    #pragma unroll
    for (int q = 0; q < 4; ++q) o[q] = fmaxf(acc3[q] + bias[q], 0.f);
    *(f32x4*)(c3buf + ((long)r * BN + b0 + b) * CN + c0) = o;
  }
}

__global__ __launch_bounds__(256) void k4_out(const float* __restrict__ c3buf,
                                              const float* __restrict__ fire,
                                              float* __restrict__ out)
{
  int t = blockIdx.x * 256 + threadIdx.x;  // over B*C/4
  int b = t >> 2, c4 = (t & 3) << 2;
  const float* fp = fire + (long)b * RN;
  f32x4 s = {};
  #pragma unroll
  for (int rr = 0; rr < RN; ++rr) {
    float fw = fp[rr];
    f32x4 v = *(const f32x4*)(c3buf + ((long)rr * BN + b) * CN + c4);
    s += fw * v;
  }
  *(f32x4*)(out + (long)b * CN + c4) = s;
}

extern "C" void kernel_launch(void* const* d_in, const int* in_sizes, int n_in,
                              void* d_out, int out_size, void* d_ws, size_t ws_size,
                              hipStream_t stream) {
  const float* data = (const float*)d_in[0];
  const float* proto = (const float*)d_in[1];
  const float* var  = (const float*)d_in[2];
  const float* Wf1  = (const float*)d_in[3];
  const float* bf1  = (const float*)d_in[4];
  const float* Wf2  = (const float*)d_in[5];
  const float* bf2  = (const float*)d_in[6];
  const float* Wf3  = (const float*)d_in[7];
  const float* bf3  = (const float*)d_in[8];
  const float* Wc1  = (const float*)d_in[9];
  const float* bc1  = (const float*)d_in[10];
  const float* Wc2  = (const float*)d_in[11];
  const float* bc2  = (const float*)d_in[12];
  const float* Wc3  = (const float*)d_in[13];
  const float* bc3  = (const float*)d_in[14];

  char* ws = (char*)d_ws;
  bf16_t* datab = (bf16_t*)(ws + OFF_DATA);
  bf16_t* Wf1p  = (bf16_t*)(ws + OFF_WF1);
  bf16_t* Wf2p  = (bf16_t*)(ws + OFF_WF2);
  bf16_t* Wc1p  = (bf16_t*)(ws + OFF_WC1);
  bf16_t* Wc2p  = (bf16_t*)(ws + OFF_WC2);
  bf16_t* Wc3p  = (bf16_t*)(ws + OFF_WC3);
  float*  fsini = (float*)(ws + OFF_FSINI);
  float*  c3buf = (float*)(ws + OFF_C3);

  float* out  = (float*)d_out;               // [B][C]
  float* fire = out + (long)BN * CN;         // [B][R]

  k0_pack<<<G_TOTAL / 256, 256, 0, stream>>>(data, Wf1, Wf2, Wc1, Wc2, Wc3, ws);
  k1_fs<<<RN * (BN / 128), 512, 0, stream>>>(data, proto, var, bf1, bf2, Wf3, bf3,
                                             Wf1p, Wf2p, fsini);
  k2_softmax<<<BN / 256, 256, 0, stream>>>(fsini, fire);
  k3_cons<<<RN * (BN / 128), 512, 0, stream>>>(datab, Wc1p, Wc2p, Wc3p, bc1, bc2, bc3, c3buf);
  k4_out<<<(BN * CN / 4) / 256, 256, 0, stream>>>(c3buf, fire, out);
}

// Round 5
// 255.144 us; speedup vs baseline: 1.4297x; 1.0382x over previous
//
#include <hip/hip_runtime.h>
#include <hip/hip_bf16.h>

// Problem dims
#define BN 16384
#define FN 256
#define RN 32
#define CN 16
#define H1N 128
#define H2N 32
#define G1N 256
#define G2N 64

typedef __bf16 bf16_t;
typedef __bf16 bf16x8 __attribute__((ext_vector_type(8)));
typedef __bf16 bf16x4 __attribute__((ext_vector_type(4)));
typedef float f32x4 __attribute__((ext_vector_type(4)));

// ---- workspace byte offsets (all 16B-aligned) ----
#define OFF_DATA   0UL          // data as bf16            [B][F]            8,388,608 B
#define OFF_WF1    8388608UL    // Wf1 packed frags        (H1,F)               65,536
#define OFF_WF2    8454144UL    // Wf2 packed frags        (H2,H1)               8,192
#define OFF_WC1    8462336UL    // Wc1 packed frags        (R,G1,F)          4,194,304
#define OFF_WC2    12656640UL   // Wc2 packed frags        (R,G2,G1)         1,048,576
#define OFF_WC3    13705216UL   // Wc3 packed frags        (R,C,G2)             65,536
#define OFF_FSINI  13770752UL   // fs_ini fp32             [B][R]            2,097,152
#define OFF_C3     15867904UL   // c3 fp32                 [R][B][C]        33,554,432

__device__ __forceinline__ f32x4 mfma16(bf16x8 a, bf16x8 b, f32x4 c) {
  return __builtin_amdgcn_mfma_f32_16x16x32_bf16(a, b, c, 0, 0, 0);
}

// Fast ELU: exp2(v*log2e)-1 instead of expm1f libcall.
__device__ __forceinline__ float elu_f(float v) {
  float e = __builtin_amdgcn_exp2f(v * 1.44269504f) - 1.0f;
  return v > 0.f ? v : e;
}

// Fragment read from an XOR-swizzled LDS tile [row][k] (row stride strideB bytes).
// Lane l gets (row = n0 + l%16, k = k0 + 8*(l/16) + e).
__device__ __forceinline__ bf16x8 lfrag(const char* base, int strideB, int n0, int k0, int lane) {
  int row = n0 + (lane & 15);
  int off = (k0 * 2 + ((lane >> 4) << 4)) ^ ((row & 7) << 4);
  return *(const bf16x8*)(base + row * strideB + off);
}

// Pack row-major W[(r,)n,k] fp32 into fragment order bf16:
// dst[(((r*KS+ks)*NT+nt)*64+lane)*8 + e] = W[r][nt*16+lane%16][ks*32+(lane/16)*8+e]
__device__ __forceinline__ void pack_frag8(const float* __restrict__ src, bf16_t* __restrict__ dst,
                                           int NT, int KS, int g) {
  int per = NT * KS * 64;
  int r = g / per;
  int local = g - r * per;
  int lane = local & 63;
  int fr = local >> 6;
  int ks = fr / NT;
  int nt = fr - ks * NT;
  int N = NT * 16, K = KS * 32;
  int n = nt * 16 + (lane & 15);
  int k = ks * 32 + ((lane >> 4) << 3);
  const float* s = src + (long)r * N * K + (long)n * K + k;
  float4 a = *(const float4*)s;
  float4 b = *(const float4*)(s + 4);
  bf16x8 o;
  o[0] = (bf16_t)a.x; o[1] = (bf16_t)a.y; o[2] = (bf16_t)a.z; o[3] = (bf16_t)a.w;
  o[4] = (bf16_t)b.x; o[5] = (bf16_t)b.y; o[6] = (bf16_t)b.z; o[7] = (bf16_t)b.w;
  *(bf16x8*)(dst + (long)g * 8) = o;
}

// group counts (each group = 8 elements)
#define G_DATA 524288
#define G_WC1  262144
#define G_WC2  65536
#define G_WF1  4096
#define G_WC3  4096
#define G_WF2  512
#define G_TOTAL (G_DATA + G_WC1 + G_WC2 + G_WF1 + G_WC3 + G_WF2) // 860,672

__global__ __launch_bounds__(256) void k0_pack(
    const float* __restrict__ data, const float* __restrict__ Wf1, const float* __restrict__ Wf2,
    const float* __restrict__ Wc1, const float* __restrict__ Wc2, const float* __restrict__ Wc3,
    char* __restrict__ ws)
{
  int g = blockIdx.x * 256 + threadIdx.x;
  if (g < G_DATA) {
    const float* s = data + (long)g * 8;
    float4 a = *(const float4*)s, b = *(const float4*)(s + 4);
    bf16x8 o;
    o[0] = (bf16_t)a.x; o[1] = (bf16_t)a.y; o[2] = (bf16_t)a.z; o[3] = (bf16_t)a.w;
    o[4] = (bf16_t)b.x; o[5] = (bf16_t)b.y; o[6] = (bf16_t)b.z; o[7] = (bf16_t)b.w;
    *(bf16x8*)((bf16_t*)(ws + OFF_DATA) + (long)g * 8) = o;
    return;
  }
  g -= G_DATA;
  if (g < G_WC1) { pack_frag8(Wc1, (bf16_t*)(ws + OFF_WC1), 16, 8, g); return; }
  g -= G_WC1;
  if (g < G_WC2) { pack_frag8(Wc2, (bf16_t*)(ws + OFF_WC2), 4, 8, g); return; }
  g -= G_WC2;
  if (g < G_WF1) { pack_frag8(Wf1, (bf16_t*)(ws + OFF_WF1), 8, 8, g); return; }
  g -= G_WF1;
  if (g < G_WC3) { pack_frag8(Wc3, (bf16_t*)(ws + OFF_WC3), 1, 2, g); return; }
  g -= G_WC3;
  if (g < G_WF2) { pack_frag8(Wf2, (bf16_t*)(ws + OFF_WF2), 2, 4, g); return; }
}

// K1: per (rule, 64-row tile): membership -> h1T -> h2T -> fs_ini
// LDS 38 KB -> 4 blocks/CU. Transposed GEMMs (weights = A-frags from global).
__global__ __launch_bounds__(512) void k1_fs(
    const float* __restrict__ data, const float* __restrict__ proto, const float* __restrict__ var,
    const float* __restrict__ bf1g, const float* __restrict__ bf2g,
    const float* __restrict__ Wf3g, const float* __restrict__ bf3g,
    const bf16_t* __restrict__ Wf1p, const bf16_t* __restrict__ Wf2p,
    float* __restrict__ fsini)
{
  __shared__ float proto_s[FN];
  __shared__ float ivar_s[FN];
  // [0,32768): mem [64][256] bf16 swz; after GEMM1: h1T [64 b][128 h] bf16 swz in [0,16384)
  // [32768,36864): h2T [32 p][64 b] bf16 flat
  __shared__ __attribute__((aligned(16))) char fs_lds[36864];

  const int r   = blockIdx.x >> 8;
  const int b0  = (blockIdx.x & 255) << 6;
  const int tid = threadIdx.x;
  const int lane = tid & 63;
  const int w   = tid >> 6;

  if (tid < FN) {
    proto_s[tid] = proto[r * FN + tid];
    float v = var[r * FN + tid];
    v = fminf(fmaxf(v, 1e-4f), 0.1f);
    ivar_s[tid] = 1.4426950408889634f * 0.5f / (v * v);  // log2(e)/(2 v^2)
  }
  __syncthreads();

  { // membership: mem[b][f] = exp2(-(x-p)^2 * ivar); 8 threads/row, 32 feats each
    const int row = tid >> 3;
    const int f0  = (tid & 7) << 5;
    const float* dp = data + (long)(b0 + row) * FN + f0;
    char* mrow = fs_lds + row * 512;
    const int sw = (row & 7) << 4;
    #pragma unroll
    for (int i = 0; i < 4; ++i) {
      const int f = f0 + i * 8;
      float4 x0 = *(const float4*)(dp + i * 8);
      float4 x1 = *(const float4*)(dp + i * 8 + 4);
      bf16x8 m; float d;
      d = x0.x - proto_s[f + 0]; m[0] = (bf16_t)__builtin_amdgcn_exp2f(-d * d * ivar_s[f + 0]);
      d = x0.y - proto_s[f + 1]; m[1] = (bf16_t)__builtin_amdgcn_exp2f(-d * d * ivar_s[f + 1]);
      d = x0.z - proto_s[f + 2]; m[2] = (bf16_t)__builtin_amdgcn_exp2f(-d * d * ivar_s[f + 2]);
      d = x0.w - proto_s[f + 3]; m[3] = (bf16_t)__builtin_amdgcn_exp2f(-d * d * ivar_s[f + 3]);
      d = x1.x - proto_s[f + 4]; m[4] = (bf16_t)__builtin_amdgcn_exp2f(-d * d * ivar_s[f + 4]);
      d = x1.y - proto_s[f + 5]; m[5] = (bf16_t)__builtin_amdgcn_exp2f(-d * d * ivar_s[f + 5]);
      d = x1.z - proto_s[f + 6]; m[6] = (bf16_t)__builtin_amdgcn_exp2f(-d * d * ivar_s[f + 6]);
      d = x1.w - proto_s[f + 7]; m[7] = (bf16_t)__builtin_amdgcn_exp2f(-d * d * ivar_s[f + 7]);
      *(bf16x8*)(mrow + ((f * 2) ^ sw)) = m;
    }
  }
  __syncthreads();

  // GEMM1: h1T[h=128][b=64] = Wf1 @ memT. 8 m-tiles x 4 n-tiles; wave: 2m x 2n
  const int mg = w >> 1;   // 0..3 (m-tiles mg*2+i)
  const int ng = w & 1;    // 0..1 (n-tiles ng*2+j)
  f32x4 acc[2][2] = {};
  #pragma unroll
  for (int ks = 0; ks < 8; ++ks) {
    bf16x8 a[2], bb[2];
    #pragma unroll
    for (int i = 0; i < 2; ++i)
      a[i] = *(const bf16x8*)(Wf1p + (((ks * 8 + mg * 2 + i) * 64 + lane)) * 8);
    #pragma unroll
    for (int j = 0; j < 2; ++j)
      bb[j] = lfrag(fs_lds, 512, (ng * 2 + j) * 16, ks * 32, lane);
    #pragma unroll
    for (int i = 0; i < 2; ++i)
      #pragma unroll
      for (int j = 0; j < 2; ++j)
        acc[i][j] = mfma16(a[i], bb[j], acc[i][j]);
  }
  __syncthreads();   // mem dead — overlay h1T in [0,16384)

  #pragma unroll
  for (int i = 0; i < 2; ++i) {
    const int hb = (mg * 2 + i) * 16 + ((lane >> 4) << 2);  // 4 consecutive h
    f32x4 bias = *(const f32x4*)(bf1g + hb);
    #pragma unroll
    for (int j = 0; j < 2; ++j) {
      const int b = (ng * 2 + j) * 16 + (lane & 15);
      bf16x4 o;
      #pragma unroll
      for (int q = 0; q < 4; ++q)
        o[q] = (bf16_t)fmaxf(acc[i][j][q] + bias[q], 0.f);
      *(bf16x4*)(fs_lds + b * 256 + ((hb * 2) ^ ((b & 7) << 4))) = o;
    }
  }
  __syncthreads();

  // GEMM2: h2T[p=32][b=64] = Wf2 @ h1T. 2 m x 4 n = 8 tiles, 1/wave
  bf16_t* h2t = (bf16_t*)(fs_lds + 32768);  // [32][64] flat
  {
    const int m = w >> 2;   // 0..1
    const int n = w & 3;    // 0..3
    f32x4 acc2 = {};
    #pragma unroll
    for (int ks = 0; ks < 4; ++ks) {
      bf16x8 a = *(const bf16x8*)(Wf2p + (((ks * 2 + m) * 64 + lane)) * 8);
      bf16x8 bb = lfrag(fs_lds, 256, n * 16, ks * 32, lane);
      acc2 = mfma16(a, bb, acc2);
    }
    const int p0 = m * 16 + ((lane >> 4) << 2);
    const int b  = n * 16 + (lane & 15);
    f32x4 bias = *(const f32x4*)(bf2g + p0);
    #pragma unroll
    for (int q = 0; q < 4; ++q)
      h2t[(p0 + q) * 64 + b] = (bf16_t)fmaxf(acc2[q] + bias[q], 0.f);
  }
  __syncthreads();

  if (tid < 64) { // fs = relu(h2 . Wf3 + bf3); h2T reads are lane-contiguous
    float s = bf3g[0];
    #pragma unroll
    for (int p = 0; p < H2N; ++p) s += (float)h2t[p * 64 + tid] * Wf3g[p];
    fsini[(long)(b0 + tid) * RN + r] = fmaxf(s, 0.f);
  }
}

__global__ __launch_bounds__(256) void k2_softmax(const float* __restrict__ fsini,
                                                  float* __restrict__ fire)
{
  int b = blockIdx.x * 256 + threadIdx.x;
  float v[RN];
  const float4* p = (const float4*)(fsini + (long)b * RN);
  #pragma unroll
  for (int i = 0; i < RN / 4; ++i) {
    float4 t = p[i];
    v[4 * i] = t.x; v[4 * i + 1] = t.y; v[4 * i + 2] = t.z; v[4 * i + 3] = t.w;
  }
  float m = v[0];
  #pragma unroll
  for (int i = 1; i < RN; ++i) m = fmaxf(m, v[i]);
  float s = 0.f;
  #pragma unroll
  for (int i = 0; i < RN; ++i) { v[i] = expf(v[i] - m); s += v[i]; }
  float inv = 1.f / s;
  float4* o = (float4*)(fire + (long)b * RN);
  #pragma unroll
  for (int i = 0; i < RN / 4; ++i) {
    float4 t; t.x = v[4 * i] * inv; t.y = v[4 * i + 1] * inv;
    t.z = v[4 * i + 2] * inv; t.w = v[4 * i + 3] * inv;
    o[i] = t;
  }
}

// K3: per (rule, 64-row tile): c1T = Wc1@dataT -> c2T = Wc2@c1T -> c3T = Wc3@c2T.
// LDS 40 KB -> 4 blocks/CU. XCD-swizzled blockIdx: each XCD owns 4 rules (weight L2 locality).
__global__ __launch_bounds__(512) void k3_cons(
    const bf16_t* __restrict__ datab,
    const bf16_t* __restrict__ Wc1p, const bf16_t* __restrict__ Wc2p, const bf16_t* __restrict__ Wc3p,
    const float* __restrict__ bc1, const float* __restrict__ bc2, const float* __restrict__ bc3,
    float* __restrict__ c3buf)
{
  __shared__ __attribute__((aligned(16))) char a_lds[64 * 512];   // data [64][256] then c1T [64][256] bf16 swz
  __shared__ __attribute__((aligned(16))) char c2_lds[64 * 128];  // c2T [64][64] bf16 swz

  // bijective XCD swizzle over 8192 blocks: xcd -> rules 4*xcd..4*xcd+3
  const int bid = blockIdx.x;
  const int xcd = bid & 7;
  const int kk  = bid >> 3;            // 0..1023
  const int r   = xcd * 4 + (kk >> 8);
  const int b0  = (kk & 255) << 6;

  const int tid = threadIdx.x;
  const int lane = tid & 63;
  const int w   = tid >> 6;

  { // stage data tile [64][256] bf16 swz; 8 threads/row, 32 elems each
    const int row = tid >> 3;
    const int e0  = (tid & 7) << 5;
    const bf16_t* sp = datab + (long)(b0 + row) * FN + e0;
    char* drow = a_lds + row * 512;
    const int sw = (row & 7) << 4;
    #pragma unroll
    for (int i = 0; i < 4; ++i) {
      bf16x8 v = *(const bf16x8*)(sp + i * 8);
      *(bf16x8*)(drow + (((e0 + i * 8) * 2) ^ sw)) = v;
    }
  }
  __syncthreads();

  // GEMM1: c1T[g1=256][b=64]. 16 m x 4 n = 64 tiles; wave: 4m x 2n
  const int wm = w >> 1;   // 0..3 (m-tiles wm*4+i)
  const int wn = w & 1;    // 0..1 (n-tiles wn*2+j)
  const bf16_t* W1 = Wc1p + (long)r * G1N * FN;
  f32x4 acc[4][2] = {};
  #pragma unroll
  for (int ks = 0; ks < 8; ++ks) {
    bf16x8 a[4], bb[2];
    #pragma unroll
    for (int i = 0; i < 4; ++i)
      a[i] = *(const bf16x8*)(W1 + (((ks * 16 + wm * 4 + i) * 64 + lane)) * 8);
    #pragma unroll
    for (int j = 0; j < 2; ++j)
      bb[j] = lfrag(a_lds, 512, (wn * 2 + j) * 16, ks * 32, lane);
    #pragma unroll
    for (int i = 0; i < 4; ++i)
      #pragma unroll
      for (int j = 0; j < 2; ++j)
        acc[i][j] = mfma16(a[i], bb[j], acc[i][j]);
  }
  __syncthreads();  // data tile dead

  // c1T epilogue: elu(acc+bias) -> bf16 [b][g1] overlay
  #pragma unroll
  for (int i = 0; i < 4; ++i) {
    const int g1b = (wm * 4 + i) * 16 + ((lane >> 4) << 2);
    f32x4 bias = *(const f32x4*)(bc1 + r * G1N + g1b);
    #pragma unroll
    for (int j = 0; j < 2; ++j) {
      const int b = (wn * 2 + j) * 16 + (lane & 15);
      bf16x4 o;
      #pragma unroll
      for (int q = 0; q < 4; ++q)
        o[q] = (bf16_t)elu_f(acc[i][j][q] + bias[q]);
      *(bf16x4*)(a_lds + b * 512 + ((g1b * 2) ^ ((b & 7) << 4))) = o;
    }
  }
  __syncthreads();

  // GEMM2: c2T[g2=64][b=64]. 4 m x 4 n = 16 tiles; wave: 1m x 2n
  const int m2 = w >> 1;   // 0..3
  const int n2 = w & 1;    // 0..1 (n-tiles n2*2+j)
  const bf16_t* W2 = Wc2p + (long)r * G2N * G1N;
  f32x4 acc2[2] = {};
  #pragma unroll
  for (int ks = 0; ks < 8; ++ks) {
    bf16x8 a = *(const bf16x8*)(W2 + (((ks * 4 + m2) * 64 + lane)) * 8);
    #pragma unroll
    for (int j = 0; j < 2; ++j) {
      bf16x8 bb = lfrag(a_lds, 512, (n2 * 2 + j) * 16, ks * 32, lane);
      acc2[j] = mfma16(a, bb, acc2[j]);
    }
  }
  {
    const int g2b = m2 * 16 + ((lane >> 4) << 2);
    f32x4 bias = *(const f32x4*)(bc2 + r * G2N + g2b);
    #pragma unroll
    for (int j = 0; j < 2; ++j) {
      const int b = (n2 * 2 + j) * 16 + (lane & 15);
      bf16x4 o;
      #pragma unroll
      for (int q = 0; q < 4; ++q)
        o[q] = (bf16_t)elu_f(acc2[j][q] + bias[q]);
      *(bf16x4*)(c2_lds + b * 128 + ((g2b * 2) ^ ((b & 7) << 4))) = o;
    }
  }
  __syncthreads();

  // GEMM3: c3T[c=16][b=64]. 1 m x 4 n, K=64; waves 0-3 only (tiny)
  if (w < 4) {
    const bf16_t* W3 = Wc3p + (long)r * CN * G2N;
    f32x4 acc3 = {};
    #pragma unroll
    for (int ks = 0; ks < 2; ++ks) {
      bf16x8 a = *(const bf16x8*)(W3 + (((long)ks * 64 + lane)) * 8);
      bf16x8 bb = lfrag(c2_lds, 128, w * 16, ks * 32, lane);
      acc3 = mfma16(a, bb, acc3);
    }
    const int c0 = ((lane >> 4) << 2);
    const int b  = w * 16 + (lane & 15);
    f32x4 bias = *(const f32x4*)(bc3 + r * CN + c0);
    f32x4 o;
    #pragma unroll
    for (int q = 0; q < 4; ++q) o[q] = fmaxf(acc3[q] + bias[q], 0.f);
    *(f32x4*)(c3buf + ((long)r * BN + b0 + b) * CN + c0) = o;
  }
}

__global__ __launch_bounds__(256) void k4_out(const float* __restrict__ c3buf,
                                              const float* __restrict__ fire,
                                              float* __restrict__ out)
{
  int t = blockIdx.x * 256 + threadIdx.x;  // over B*C/4
  int b = t >> 2, c4 = (t & 3) << 2;
  const float* fp = fire + (long)b * RN;
  f32x4 s = {};
  #pragma unroll
  for (int rr = 0; rr < RN; ++rr) {
    float fw = fp[rr];
    f32x4 v = *(const f32x4*)(c3buf + ((long)rr * BN + b) * CN + c4);
    s += fw * v;
  }
  *(f32x4*)(out + (long)b * CN + c4) = s;
}

extern "C" void kernel_launch(void* const* d_in, const int* in_sizes, int n_in,
                              void* d_out, int out_size, void* d_ws, size_t ws_size,
                              hipStream_t stream) {
  const float* data = (const float*)d_in[0];
  const float* proto = (const float*)d_in[1];
  const float* var  = (const float*)d_in[2];
  const float* Wf1  = (const float*)d_in[3];
  const float* bf1  = (const float*)d_in[4];
  const float* Wf2  = (const float*)d_in[5];
  const float* bf2  = (const float*)d_in[6];
  const float* Wf3  = (const float*)d_in[7];
  const float* bf3  = (const float*)d_in[8];
  const float* Wc1  = (const float*)d_in[9];
  const float* bc1  = (const float*)d_in[10];
  const float* Wc2  = (const float*)d_in[11];
  const float* bc2  = (const float*)d_in[12];
  const float* Wc3  = (const float*)d_in[13];
  const float* bc3  = (const float*)d_in[14];

  char* ws = (char*)d_ws;
  bf16_t* datab = (bf16_t*)(ws + OFF_DATA);
  bf16_t* Wf1p  = (bf16_t*)(ws + OFF_WF1);
  bf16_t* Wf2p  = (bf16_t*)(ws + OFF_WF2);
  bf16_t* Wc1p  = (bf16_t*)(ws + OFF_WC1);
  bf16_t* Wc2p  = (bf16_t*)(ws + OFF_WC2);
  bf16_t* Wc3p  = (bf16_t*)(ws + OFF_WC3);
  float*  fsini = (float*)(ws + OFF_FSINI);
  float*  c3buf = (float*)(ws + OFF_C3);

  float* out  = (float*)d_out;               // [B][C]
  float* fire = out + (long)BN * CN;         // [B][R]

  k0_pack<<<G_TOTAL / 256, 256, 0, stream>>>(data, Wf1, Wf2, Wc1, Wc2, Wc3, ws);
  k1_fs<<<RN * (BN / 64), 512, 0, stream>>>(data, proto, var, bf1, bf2, Wf3, bf3,
                                            Wf1p, Wf2p, fsini);
  k2_softmax<<<BN / 256, 256, 0, stream>>>(fsini, fire);
  k3_cons<<<RN * (BN / 64), 512, 0, stream>>>(datab, Wc1p, Wc2p, Wc3p, bc1, bc2, bc3, c3buf);
  k4_out<<<(BN * CN / 4) / 256, 256, 0, stream>>>(c3buf, fire, out);
}